// Round 18
// baseline (554.358 us; speedup 1.0000x reference)
//
#include <hip/hip_runtime.h>
#include <hip/hip_bf16.h>
#include <math.h>

typedef __attribute__((ext_vector_type(8))) short short8;
typedef __attribute__((ext_vector_type(4))) short sv4;
typedef __attribute__((ext_vector_type(4))) float f32x4;
typedef unsigned int u32;

#define BT_ 384
#define N_ 716
#define C_ 256
#define H_ 8
#define D_ 32
#define MROWS (BT_ * N_)   /* 274944 */
#define NT_ (MROWS / 64)   /* 4296 row-tiles of 64 */
#define SCALE_ 0.17677669529663687f  /* 32^-0.5 */
#define INVN_ (1.0f / 716.0f)

__device__ __forceinline__ void gload_lds16(const void* g, void* l) {
    __builtin_amdgcn_global_load_lds(
        (const __attribute__((address_space(1))) u32*)g,
        (__attribute__((address_space(3))) u32*)l, 16, 0, 0);
}

// ---------------------------------------------------------------------------
// Assemble bf16 weight matrices + fused qkv bias. Wqkv_b[768][256], Wo_b[256][256]
// ---------------------------------------------------------------------------
__global__ void prep_weights(const float* __restrict__ Wq, const float* __restrict__ bq,
                             const float* __restrict__ Wk, const float* __restrict__ bk,
                             const float* __restrict__ Wv, const float* __restrict__ bv,
                             const float* __restrict__ Wo,
                             __hip_bfloat16* __restrict__ wqkv, float* __restrict__ bqkv,
                             __hip_bfloat16* __restrict__ wo) {
    int idx = blockIdx.x * 256 + threadIdx.x;
    if (idx < 768 * 256) {
        int o = idx >> 8, c = idx & 255;
        const float* W = (o < 256) ? Wq : ((o < 512) ? Wk : Wv);
        int oo = o & 255;
        wqkv[idx] = __float2bfloat16(W[oo * 256 + c]);
    }
    if (idx < 256 * 256) wo[idx] = __float2bfloat16(Wo[idx]);
    if (idx < 768) bqkv[idx] = (idx < 256) ? bq[idx] : ((idx < 512) ? bk[idx - 256] : bv[idx - 512]);
}

// ---------------------------------------------------------------------------
// x fp32 -> bf16 (vectorized float4/short4), plus per-(bt,channel) col sums
// grid (384, 4), block 256.
// ---------------------------------------------------------------------------
__global__ __launch_bounds__(256)
void convert_x(const float* __restrict__ x, __hip_bfloat16* __restrict__ xb,
               float* __restrict__ msum) {
    int bt = blockIdx.x, chunk = blockIdx.y;
    int t = threadIdx.x;
    int c4 = (t & 63) * 4;
    int r0 = t >> 6;
    size_t base = ((size_t)bt * N_ + (size_t)chunk * 179) * C_;
    float s0 = 0.f, s1 = 0.f, s2 = 0.f, s3 = 0.f;
    for (int r = r0; r < 179; r += 4) {
        float4 f = *(const float4*)&x[base + (size_t)r * C_ + c4];
        union { sv4 v; __hip_bfloat16 h[4]; } u;
        u.h[0] = __float2bfloat16(f.x);
        u.h[1] = __float2bfloat16(f.y);
        u.h[2] = __float2bfloat16(f.z);
        u.h[3] = __float2bfloat16(f.w);
        *(sv4*)&xb[base + (size_t)r * C_ + c4] = u.v;
        s0 += f.x; s1 += f.y; s2 += f.z; s3 += f.w;
    }
    atomicAdd(&msum[bt * C_ + c4 + 0], s0);
    atomicAdd(&msum[bt * C_ + c4 + 1], s1);
    atomicAdd(&msum[bt * C_ + c4 + 2], s2);
    atomicAdd(&msum[bt * C_ + c4 + 3], s3);
}

// ---------------------------------------------------------------------------
// Grouped 2-layer MLP -> per-channel 3-tap conv weights rw[bt][768]
// ---------------------------------------------------------------------------
__global__ __launch_bounds__(256)
void mlp_rw(const float* __restrict__ msum, const float* __restrict__ w1,
            const float* __restrict__ b1, const float* __restrict__ w2,
            const float* __restrict__ b2, float* __restrict__ rw) {
    int bt = blockIdx.x;
    int t = threadIdx.x;
    __shared__ float m_l[256];
    __shared__ float h1_l[256];
    m_l[t] = msum[bt * 256 + t] * INVN_;
    __syncthreads();
    int g = t >> 5;
    float a = b1[t];
    #pragma unroll
    for (int i = 0; i < 32; ++i) a += m_l[g * 32 + i] * w1[t * 32 + i];
    h1_l[t] = 0.5f * a * (1.0f + erff(a * 0.70710678118654752f));
    __syncthreads();
    for (int o = t; o < 768; o += 256) {
        int gg = o / 96;
        float s = b2[o];
        #pragma unroll
        for (int i = 0; i < 32; ++i) s += h1_l[gg * 32 + i] * w2[o * 32 + i];
        rw[bt * 768 + o] = s;
    }
}

// ---------------------------------------------------------------------------
// Persistent B-resident GEMM v2 (R9/R15, best measured). bf16 output path
// used for the QKV projection. grid GRIDX*256, block 256.
// ---------------------------------------------------------------------------
template<int NCOLS, int GRIDX, bool OUT_BF16>
__global__ __launch_bounds__(256, 2)
void gemm_persist(const __hip_bfloat16* __restrict__ A, const __hip_bfloat16* __restrict__ Bm,
                  const float* __restrict__ bias, void* __restrict__ outp) {
    __shared__ __align__(16) __hip_bfloat16 As[2][64 * 256];   // 2 x 32KB
    const int L = blockIdx.x;
    const int xcd = L & 7, w = L >> 3;
    const int cb = w % GRIDX;
    const int ib = xcd * 32 + w / GRIDX;
    const int tid = threadIdx.x;
    const int lane = tid & 63;
    const int wave = tid >> 6;
    const int wn = wave;
    const int colBase = cb * 128;
    const int l15 = lane & 15, lq = lane >> 4;
    const int lrow2 = lane >> 5;
    const int p = lane & 31;

    auto stageA = [&](int rt, int buf) {
        #pragma unroll
        for (int i = 0; i < 8; ++i) {
            int r = wave * 16 + 2 * i + lrow2;
            const __hip_bfloat16* g = A + ((size_t)rt * 64 + r) * 256 + ((p ^ (r & 7)) * 8);
            gload_lds16(g, &As[buf][(wave * 16 + 2 * i) * 256]);
        }
    };

    stageA(ib, 0);

    short8 bf[2][8];
    #pragma unroll
    for (int n = 0; n < 2; ++n)
        #pragma unroll
        for (int ks = 0; ks < 8; ++ks)
            bf[n][ks] = *(const short8*)&Bm[(size_t)(colBase + wn * 32 + n * 16 + l15) * 256 + ks * 32 + lq * 8];
    float biasr[2];
    #pragma unroll
    for (int n = 0; n < 2; ++n)
        biasr[n] = bias[colBase + wn * 32 + n * 16 + l15];

    asm volatile("s_waitcnt vmcnt(0)" ::: "memory");
    __builtin_amdgcn_s_barrier();

    int buf = 0;
    for (int rt = ib; rt < NT_; rt += 256) {
        int rtn = rt + 256;
        if (rtn < NT_) stageA(rtn, buf ^ 1);

        f32x4 acc[4][2] = {};
        #pragma unroll
        for (int ks = 0; ks < 8; ++ks) {
            short8 af[4];
            #pragma unroll
            for (int m = 0; m < 4; ++m) {
                int row = m * 16 + l15;
                af[m] = *(const short8*)&As[buf][row * 256 + (((ks * 4 + lq) ^ (row & 7)) * 8)];
            }
            #pragma unroll
            for (int m = 0; m < 4; ++m)
                #pragma unroll
                for (int n = 0; n < 2; ++n)
                    acc[m][n] = __builtin_amdgcn_mfma_f32_16x16x32_bf16(af[m], bf[n][ks], acc[m][n], 0, 0, 0);
        }
        asm volatile("s_waitcnt lgkmcnt(0)" ::: "memory");
        __builtin_amdgcn_s_barrier();

        if constexpr (OUT_BF16) {
            __hip_bfloat16* Cs = &As[buf][0];  // [64][136]
            #pragma unroll
            for (int m = 0; m < 4; ++m)
                #pragma unroll
                for (int n = 0; n < 2; ++n) {
                    int col = wn * 32 + n * 16 + l15;
                    #pragma unroll
                    for (int j = 0; j < 4; ++j)
                        Cs[(m * 16 + lq * 4 + j) * 136 + col] =
                            __float2bfloat16(acc[m][n][j] + biasr[n]);
                }
            asm volatile("s_waitcnt lgkmcnt(0)" ::: "memory");
            __builtin_amdgcn_s_barrier();
            int row = tid >> 2, cq = tid & 3;
            __hip_bfloat16* og = (__hip_bfloat16*)outp + ((size_t)rt * 64 + row) * NCOLS + colBase;
            #pragma unroll
            for (int i = 0; i < 4; ++i) {
                int col = cq * 8 + i * 32;
                *(short8*)&og[col] = *(const short8*)&Cs[row * 136 + col];
            }
            asm volatile("s_waitcnt vmcnt(2) lgkmcnt(0)" ::: "memory");
            __builtin_amdgcn_s_barrier();
        } else {
            float* Cs = (float*)&As[buf][0];   // [32][132] per pass
            #pragma unroll
            for (int pp = 0; pp < 2; ++pp) {
                #pragma unroll
                for (int mm = 0; mm < 2; ++mm) {
                    int m = 2 * pp + mm;
                    #pragma unroll
                    for (int n = 0; n < 2; ++n) {
                        int col = wn * 32 + n * 16 + l15;
                        #pragma unroll
                        for (int j = 0; j < 4; ++j)
                            Cs[(mm * 16 + lq * 4 + j) * 132 + col] = acc[m][n][j] + biasr[n];
                    }
                }
                asm volatile("s_waitcnt lgkmcnt(0)" ::: "memory");
                __builtin_amdgcn_s_barrier();
                int row = tid >> 3, k = tid & 7;
                float* og = (float*)outp + ((size_t)rt * 64 + pp * 32 + row) * NCOLS + colBase;
                #pragma unroll
                for (int i = 0; i < 4; ++i) {
                    int col = k * 4 + i * 32;
                    *(float4*)&og[col] = *(const float4*)&Cs[row * 132 + col];
                }
                asm volatile("s_waitcnt lgkmcnt(0)" ::: "memory");
                __builtin_amdgcn_s_barrier();
            }
            asm volatile("s_waitcnt vmcnt(4) lgkmcnt(0)" ::: "memory");
            __builtin_amdgcn_s_barrier();
        }
        buf ^= 1;
    }
}

// ---------------------------------------------------------------------------
// MFMA reduce_kv (R8): one block per bt, 8 waves = 8 heads.
// ---------------------------------------------------------------------------
__global__ __launch_bounds__(512, 2)
void reduce_kv(const __hip_bfloat16* __restrict__ qkv, __hip_bfloat16* __restrict__ kv2t,
               float* __restrict__ vmeanb) {
    __shared__ __align__(16) __hip_bfloat16 T[512 * 64];   // 64 KB
    const int bt = blockIdx.x;
    const int tid = threadIdx.x;
    const int lane = tid & 63;
    const int h = tid >> 6;
    const int l15 = lane & 15, lq = lane >> 4;
    const int co = tid >> 3;
    const int np3 = tid & 7;
    const size_t rowbase = (size_t)bt * N_;

    union S8 { short8 v; unsigned short u[8]; };
    const short8 zero8 = {0, 0, 0, 0, 0, 0, 0, 0};

    auto issue_loads = [&](int n0, S8* Aq, S8* Bq) {
        #pragma unroll
        for (int s = 0; s < 4; ++s) {
            int n = n0 + 2 * (np3 + 8 * s);
            Aq[s].v = (n < N_)     ? *(const short8*)&qkv[(rowbase + n) * 768 + 256 + co * 8] : zero8;
            Bq[s].v = (n + 1 < N_) ? *(const short8*)&qkv[(rowbase + n + 1) * 768 + 256 + co * 8] : zero8;
        }
    };
    auto write_lds = [&](S8* Aq, S8* Bq) {
        #pragma unroll
        for (int s = 0; s < 4; ++s) {
            int r = 2 * (np3 + 8 * s);
            int slotbase = ((r >> 3));
            #pragma unroll
            for (int j = 0; j < 8; ++j) {
                int c = co * 8 + j;
                u32 wv = (u32)Aq[s].u[j] | ((u32)Bq[s].u[j] << 16);
                int off = c * 64 + ((slotbase ^ (c & 7)) << 3) + (r & 7);
                *(u32*)&T[off] = wv;
            }
        }
    };

    S8 bufA[4], bufB[4], nxtA[4], nxtB[4];
    issue_loads(0, bufA, bufB);

    f32x4 acc[2][2] = {};
    f32x4 acck[2] = {};
    f32x4 accv[2] = {};
    S8 ones;
    #pragma unroll
    for (int j = 0; j < 8; ++j) ones.u[j] = 0x3F80;   // bf16 1.0

    for (int chunk = 0; chunk < 12; ++chunk) {
        if (chunk < 11) issue_loads((chunk + 1) * 64, nxtA, nxtB);
        write_lds(bufA, bufB);
        __syncthreads();
        #pragma unroll
        for (int nc = 0; nc < 2; ++nc) {
            short8 af[2], bfr[2];
            int slot = nc * 4 + lq;
            #pragma unroll
            for (int dh = 0; dh < 2; ++dh) {
                int c = h * 32 + dh * 16 + l15;
                af[dh] = *(const short8*)&T[c * 64 + ((slot ^ (c & 7)) << 3)];
            }
            #pragma unroll
            for (int eh = 0; eh < 2; ++eh) {
                int c = 256 + h * 32 + eh * 16 + l15;
                bfr[eh] = *(const short8*)&T[c * 64 + ((slot ^ (c & 7)) << 3)];
            }
            #pragma unroll
            for (int dh = 0; dh < 2; ++dh)
                #pragma unroll
                for (int eh = 0; eh < 2; ++eh)
                    acc[dh][eh] = __builtin_amdgcn_mfma_f32_16x16x32_bf16(af[dh], bfr[eh], acc[dh][eh], 0, 0, 0);
            #pragma unroll
            for (int dh = 0; dh < 2; ++dh)
                acck[dh] = __builtin_amdgcn_mfma_f32_16x16x32_bf16(af[dh], ones.v, acck[dh], 0, 0, 0);
            #pragma unroll
            for (int eh = 0; eh < 2; ++eh)
                accv[eh] = __builtin_amdgcn_mfma_f32_16x16x32_bf16(ones.v, bfr[eh], accv[eh], 0, 0, 0);
        }
        __syncthreads();
        #pragma unroll
        for (int s = 0; s < 4; ++s) { bufA[s] = nxtA[s]; bufB[s] = nxtB[s]; }
    }

    const int bh = bt * 8 + h;
    #pragma unroll
    for (int eh = 0; eh < 2; ++eh) {
        int e = eh * 16 + l15;
        float vme = accv[eh][0] * INVN_;
        #pragma unroll
        for (int dh = 0; dh < 2; ++dh) {
            union { sv4 v; __hip_bfloat16 x[4]; } o;
            #pragma unroll
            for (int j = 0; j < 4; ++j) {
                float km = acck[dh][j] * INVN_;
                float val = acc[dh][eh][j] * (SCALE_ * INVN_) - SCALE_ * km * vme;
                o.x[j] = __float2bfloat16(val);
            }
            *(sv4*)&kv2t[(size_t)bh * 1024 + e * 32 + dh * 16 + lq * 4] = o.v;
        }
        if (lq == 0) vmeanb[bh * 32 + e] = vme;
    }
}

// ---------------------------------------------------------------------------
// fuse_zout: attn (q@kv2t + vmean) -> in-place 3-tap conv -> out projection,
// all on one 64x256 LDS tile (GEMM-swizzled). Wo fragments in registers
// (wave = 32 cols, bf[2][8]). f32 epilogue: FOUR passes of 16 rows through
// Cs[16][264] (16.9KB, fits the dead-kvl RB region; fixes R17's stride-136
// overflow with 256 block-wide columns).
// grid (384, 12), block 512 (8 waves). LDS = 32KB AZ + 17KB RB.
// ---------------------------------------------------------------------------
__global__ __launch_bounds__(512, 2)
void fuse_zout(const __hip_bfloat16* __restrict__ qkv, const __hip_bfloat16* __restrict__ kv2t,
               const float* __restrict__ vmeanb, const float* __restrict__ rw,
               const __hip_bfloat16* __restrict__ wo, const float* __restrict__ bo,
               float* __restrict__ outp) {
    __shared__ __align__(16) __hip_bfloat16 AZ[64 * 256];   // 32 KB, swizzled tile
    __shared__ __align__(16) char RB[17408];                // kvl 16KB -> Cs f32[16][264]
    __hip_bfloat16* kvl = (__hip_bfloat16*)RB;

    const int bt = blockIdx.x;
    const int n0 = blockIdx.y * 64;
    const int rows = (N_ - n0 < 64) ? (N_ - n0) : 64;
    const int t = threadIdx.x;
    const int lane = t & 63;
    const int w = t >> 6;                 // wave 0..7
    const int l15 = lane & 15, lq = lane >> 4;
    const size_t rowbase = (size_t)bt * N_;

    // Wo fragments + bias: wave w owns output cols w*32..+32
    short8 bf[2][8];
    #pragma unroll
    for (int n = 0; n < 2; ++n)
        #pragma unroll
        for (int ks = 0; ks < 8; ++ks)
            bf[n][ks] = *(const short8*)&wo[(size_t)(w * 32 + n * 16 + l15) * 256 + ks * 32 + lq * 8];
    float biasr[2];
    #pragma unroll
    for (int n = 0; n < 2; ++n) biasr[n] = bo[w * 32 + n * 16 + l15];

    // stage kv2t[bt] slice (16 KB)
    {
        const __hip_bfloat16* src = kv2t + (size_t)bt * 8192;
        #pragma unroll
        for (int i = 0; i < 2; ++i) {
            int off = (t + i * 512) * 8;
            *(short8*)&kvl[off] = *(const short8*)&src[off];
        }
    }
    __syncthreads();

    // ---- phase 1: attn = q @ kv2t + vmean -> AZ (swizzled) ----
    {
        int r0 = (w & 3) * 16;            // wave's 16-row slice
        int hb = (w >> 2) * 4;            // wave's 4 heads
        int gn = n0 + r0 + l15; if (gn > N_ - 1) gn = N_ - 1;
        const __hip_bfloat16* qrow = qkv + (rowbase + gn) * 768;
        #pragma unroll
        for (int hh = 0; hh < 4; ++hh) {
            int h = hb + hh;
            short8 af = *(const short8*)&qrow[h * 32 + lq * 8];
            #pragma unroll
            for (int half = 0; half < 2; ++half) {
                short8 kb = *(const short8*)&kvl[h * 1024 + (half * 16 + l15) * 32 + lq * 8];
                f32x4 a = {};
                a = __builtin_amdgcn_mfma_f32_16x16x32_bf16(af, kb, a, 0, 0, 0);
                int col = h * 32 + half * 16 + l15;
                float vm = vmeanb[bt * 256 + col];
                #pragma unroll
                for (int j = 0; j < 4; ++j) {
                    int r = r0 + lq * 4 + j;
                    AZ[r * 256 + ((((col >> 3) ^ (r & 7)) << 3) | (col & 7))] =
                        __float2bfloat16(a[j] + vm);
                }
            }
        }
    }
    __syncthreads();

    // ---- phase 2: in-place conv: AZ[r][c] += rw0*v[r-1]+rw1*v[r]+rw2*v[r+1] ----
    {
        int rbeg = (t >> 6) * 8;
        int c4 = (t & 63) * 4;
        if (rbeg < rows) {
            int rend = rbeg + 8; if (rend > rows) rend = rows;
            float w0[4], w1_[4], w2_[4];
            #pragma unroll
            for (int u = 0; u < 4; ++u) {
                w0[u]  = rw[bt * 768 + (c4 + u) * 3 + 0];
                w1_[u] = rw[bt * 768 + (c4 + u) * 3 + 1];
                w2_[u] = rw[bt * 768 + (c4 + u) * 3 + 2];
            }
            union U4 { sv4 v; __hip_bfloat16 h[4]; };
            auto loadv = [&](int gn, float* dst) {
                if (gn >= 0 && gn < N_) {
                    U4 u; u.v = *(const sv4*)&qkv[(rowbase + gn) * 768 + 512 + c4];
                    #pragma unroll
                    for (int uu = 0; uu < 4; ++uu) dst[uu] = __bfloat162float(u.h[uu]);
                } else {
                    #pragma unroll
                    for (int uu = 0; uu < 4; ++uu) dst[uu] = 0.0f;
                }
            };
            float vp[4], vc[4], vn[4];
            loadv(n0 + rbeg - 1, vp);
            loadv(n0 + rbeg, vc);
            for (int r = rbeg; r < rend; ++r) {
                int gn = n0 + r;
                loadv(gn + 1, vn);
                int base = r * 256 + ((((c4 >> 3) ^ (r & 7)) << 3) | (c4 & 7));
                U4 az; az.v = *(const sv4*)&AZ[base];
                U4 zv;
                #pragma unroll
                for (int u = 0; u < 4; ++u) {
                    float s = __bfloat162float(az.h[u]) + w0[u] * vp[u]
                              + w1_[u] * vc[u] + w2_[u] * vn[u];
                    zv.h[u] = __float2bfloat16(s);
                }
                *(sv4*)&AZ[base] = zv.v;
                #pragma unroll
                for (int u = 0; u < 4; ++u) { vp[u] = vc[u]; vc[u] = vn[u]; }
            }
        }
    }
    __syncthreads();

    // ---- phase 3: out = Z @ Wo^T + bo; A from AZ (LDS), B in regs ----
    f32x4 acc[4][2] = {};
    #pragma unroll
    for (int ks = 0; ks < 8; ++ks) {
        short8 af[4];
        #pragma unroll
        for (int m = 0; m < 4; ++m) {
            int row = m * 16 + l15;
            af[m] = *(const short8*)&AZ[row * 256 + (((ks * 4 + lq) ^ (row & 7)) << 3)];
        }
        #pragma unroll
        for (int m = 0; m < 4; ++m)
            #pragma unroll
            for (int n = 0; n < 2; ++n)
                acc[m][n] = __builtin_amdgcn_mfma_f32_16x16x32_bf16(af[m], bf[n][ks], acc[m][n], 0, 0, 0);
    }

    // ---- epilogue: 4 passes of 16 rows through Cs[16][264] (kvl dead) ----
    float* Cs = (float*)RB;   // 16 * 264 * 4 = 16896 B <= 17408 B
    #pragma unroll
    for (int pp = 0; pp < 4; ++pp) {
        asm volatile("s_waitcnt lgkmcnt(0)" ::: "memory");
        __builtin_amdgcn_s_barrier();     // region free / prev-pass reads done
        #pragma unroll
        for (int n = 0; n < 2; ++n) {
            int col = w * 32 + n * 16 + l15;
            #pragma unroll
            for (int j = 0; j < 4; ++j)
                Cs[(lq * 4 + j) * 264 + col] = acc[pp][n][j] + biasr[n];
        }
        asm volatile("s_waitcnt lgkmcnt(0)" ::: "memory");
        __builtin_amdgcn_s_barrier();
        int row = t >> 5, kk = t & 31;    // 16 rows x 32 col-quads
        int grow = pp * 16 + row;
        if (grow < rows) {
            float* og = outp + (rowbase + n0 + grow) * 256;
            #pragma unroll
            for (int i = 0; i < 2; ++i) {
                int col = kk * 4 + i * 128;
                *(float4*)&og[col] = *(const float4*)&Cs[row * 264 + col];
            }
        }
    }
}

// ---------------------------------------------------------------------------
extern "C" void kernel_launch(void* const* d_in, const int* in_sizes, int n_in,
                              void* d_out, int out_size, void* d_ws, size_t ws_size,
                              hipStream_t stream) {
    (void)in_sizes; (void)n_in; (void)out_size; (void)ws_size;
    const float* x  = (const float*)d_in[0];
    const float* Wq = (const float*)d_in[1];  const float* bq = (const float*)d_in[2];
    const float* Wk = (const float*)d_in[3];  const float* bk = (const float*)d_in[4];
    const float* Wv = (const float*)d_in[5];  const float* bv = (const float*)d_in[6];
    const float* Wo = (const float*)d_in[7];  const float* bo = (const float*)d_in[8];
    const float* w1 = (const float*)d_in[9];  const float* b1 = (const float*)d_in[10];
    const float* w2 = (const float*)d_in[11]; const float* b2 = (const float*)d_in[12];
    float* out = (float*)d_out;

    char* ws = (char*)d_ws;
    size_t off = 0;
    auto take = [&](size_t bytes) -> char* {
        char* p = ws + off;
        off = (off + bytes + 255) & ~(size_t)255;
        return p;
    };

    __hip_bfloat16* qkv   = (__hip_bfloat16*)take((size_t)MROWS * 768 * 2);
    __hip_bfloat16* xb    = (__hip_bfloat16*)take((size_t)MROWS * 256 * 2);
    __hip_bfloat16* wqkv  = (__hip_bfloat16*)take(768 * 256 * 2);
    __hip_bfloat16* wo    = (__hip_bfloat16*)take(256 * 256 * 2);
    float* bqkv   = (float*)take(768 * 4);
    float* msum   = (float*)take(384 * 256 * 4);
    float* rw     = (float*)take(384 * 768 * 4);
    __hip_bfloat16* kv2t = (__hip_bfloat16*)take((size_t)384 * 8192 * 2);
    float* vmeanb = (float*)take(384 * 256 * 4);

    hipMemsetAsync(msum, 0, 384 * 256 * 4, stream);

    prep_weights<<<768, 256, 0, stream>>>(Wq, bq, Wk, bk, Wv, bv, Wo, wqkv, bqkv, wo);
    convert_x<<<dim3(384, 4), 256, 0, stream>>>(x, xb, msum);
    mlp_rw<<<384, 256, 0, stream>>>(msum, w1, b1, w2, b2, rw);
    // QKV projection: [274944,256] x [768,256]^T -> bf16 qkv, bias fused
    gemm_persist<768, 6, true><<<1536, 256, 0, stream>>>(xb, wqkv, bqkv, qkv);
    reduce_kv<<<384, 512, 0, stream>>>(qkv, kv2t, vmeanb);
    // Fused: attn + conv + output projection -> out (f32), Z never materialized
    fuse_zout<<<dim3(384, 12), 512, 0, stream>>>(qkv, kv2t, vmeanb, rw, wo, bo, out);
}

// Round 19
// 526.605 us; speedup vs baseline: 1.0527x; 1.0527x over previous
//
#include <hip/hip_runtime.h>
#include <hip/hip_bf16.h>
#include <math.h>

typedef __attribute__((ext_vector_type(8))) short short8;
typedef __attribute__((ext_vector_type(4))) short sv4;
typedef __attribute__((ext_vector_type(4))) float f32x4;
typedef unsigned int u32;

#define BT_ 384
#define N_ 716
#define C_ 256
#define H_ 8
#define D_ 32
#define MROWS (BT_ * N_)   /* 274944 */
#define NT_ (MROWS / 64)   /* 4296 row-tiles of 64 */
#define SCALE_ 0.17677669529663687f  /* 32^-0.5 */
#define INVN_ (1.0f / 716.0f)

__device__ __forceinline__ void gload_lds16(const void* g, void* l) {
    __builtin_amdgcn_global_load_lds(
        (const __attribute__((address_space(1))) u32*)g,
        (__attribute__((address_space(3))) u32*)l, 16, 0, 0);
}

// ---------------------------------------------------------------------------
// Assemble bf16 weight matrices + fused qkv bias. Wqkv_b[768][256], Wo_b[256][256]
// ---------------------------------------------------------------------------
__global__ void prep_weights(const float* __restrict__ Wq, const float* __restrict__ bq,
                             const float* __restrict__ Wk, const float* __restrict__ bk,
                             const float* __restrict__ Wv, const float* __restrict__ bv,
                             const float* __restrict__ Wo,
                             __hip_bfloat16* __restrict__ wqkv, float* __restrict__ bqkv,
                             __hip_bfloat16* __restrict__ wo) {
    int idx = blockIdx.x * 256 + threadIdx.x;
    if (idx < 768 * 256) {
        int o = idx >> 8, c = idx & 255;
        const float* W = (o < 256) ? Wq : ((o < 512) ? Wk : Wv);
        int oo = o & 255;
        wqkv[idx] = __float2bfloat16(W[oo * 256 + c]);
    }
    if (idx < 256 * 256) wo[idx] = __float2bfloat16(Wo[idx]);
    if (idx < 768) bqkv[idx] = (idx < 256) ? bq[idx] : ((idx < 512) ? bk[idx - 256] : bv[idx - 512]);
}

// ---------------------------------------------------------------------------
// x fp32 -> bf16 (vectorized float4/short4), plus per-(bt,channel) col sums
// grid (384, 4), block 256.
// ---------------------------------------------------------------------------
__global__ __launch_bounds__(256)
void convert_x(const float* __restrict__ x, __hip_bfloat16* __restrict__ xb,
               float* __restrict__ msum) {
    int bt = blockIdx.x, chunk = blockIdx.y;
    int t = threadIdx.x;
    int c4 = (t & 63) * 4;
    int r0 = t >> 6;
    size_t base = ((size_t)bt * N_ + (size_t)chunk * 179) * C_;
    float s0 = 0.f, s1 = 0.f, s2 = 0.f, s3 = 0.f;
    for (int r = r0; r < 179; r += 4) {
        float4 f = *(const float4*)&x[base + (size_t)r * C_ + c4];
        union { sv4 v; __hip_bfloat16 h[4]; } u;
        u.h[0] = __float2bfloat16(f.x);
        u.h[1] = __float2bfloat16(f.y);
        u.h[2] = __float2bfloat16(f.z);
        u.h[3] = __float2bfloat16(f.w);
        *(sv4*)&xb[base + (size_t)r * C_ + c4] = u.v;
        s0 += f.x; s1 += f.y; s2 += f.z; s3 += f.w;
    }
    atomicAdd(&msum[bt * C_ + c4 + 0], s0);
    atomicAdd(&msum[bt * C_ + c4 + 1], s1);
    atomicAdd(&msum[bt * C_ + c4 + 2], s2);
    atomicAdd(&msum[bt * C_ + c4 + 3], s3);
}

// ---------------------------------------------------------------------------
// Grouped 2-layer MLP -> per-channel 3-tap conv weights rw[bt][768]
// ---------------------------------------------------------------------------
__global__ __launch_bounds__(256)
void mlp_rw(const float* __restrict__ msum, const float* __restrict__ w1,
            const float* __restrict__ b1, const float* __restrict__ w2,
            const float* __restrict__ b2, float* __restrict__ rw) {
    int bt = blockIdx.x;
    int t = threadIdx.x;
    __shared__ float m_l[256];
    __shared__ float h1_l[256];
    m_l[t] = msum[bt * 256 + t] * INVN_;
    __syncthreads();
    int g = t >> 5;
    float a = b1[t];
    #pragma unroll
    for (int i = 0; i < 32; ++i) a += m_l[g * 32 + i] * w1[t * 32 + i];
    h1_l[t] = 0.5f * a * (1.0f + erff(a * 0.70710678118654752f));
    __syncthreads();
    for (int o = t; o < 768; o += 256) {
        int gg = o / 96;
        float s = b2[o];
        #pragma unroll
        for (int i = 0; i < 32; ++i) s += h1_l[gg * 32 + i] * w2[o * 32 + i];
        rw[bt * 768 + o] = s;
    }
}

// ---------------------------------------------------------------------------
// Persistent B-resident GEMM v2 (R9/R15, best measured). bf16 output path
// used for the QKV projection. grid GRIDX*256, block 256.
// ---------------------------------------------------------------------------
template<int NCOLS, int GRIDX, bool OUT_BF16>
__global__ __launch_bounds__(256, 2)
void gemm_persist(const __hip_bfloat16* __restrict__ A, const __hip_bfloat16* __restrict__ Bm,
                  const float* __restrict__ bias, void* __restrict__ outp) {
    __shared__ __align__(16) __hip_bfloat16 As[2][64 * 256];   // 2 x 32KB
    const int L = blockIdx.x;
    const int xcd = L & 7, w = L >> 3;
    const int cb = w % GRIDX;
    const int ib = xcd * 32 + w / GRIDX;
    const int tid = threadIdx.x;
    const int lane = tid & 63;
    const int wave = tid >> 6;
    const int wn = wave;
    const int colBase = cb * 128;
    const int l15 = lane & 15, lq = lane >> 4;
    const int lrow2 = lane >> 5;
    const int p = lane & 31;

    auto stageA = [&](int rt, int buf) {
        #pragma unroll
        for (int i = 0; i < 8; ++i) {
            int r = wave * 16 + 2 * i + lrow2;
            const __hip_bfloat16* g = A + ((size_t)rt * 64 + r) * 256 + ((p ^ (r & 7)) * 8);
            gload_lds16(g, &As[buf][(wave * 16 + 2 * i) * 256]);
        }
    };

    stageA(ib, 0);

    short8 bf[2][8];
    #pragma unroll
    for (int n = 0; n < 2; ++n)
        #pragma unroll
        for (int ks = 0; ks < 8; ++ks)
            bf[n][ks] = *(const short8*)&Bm[(size_t)(colBase + wn * 32 + n * 16 + l15) * 256 + ks * 32 + lq * 8];
    float biasr[2];
    #pragma unroll
    for (int n = 0; n < 2; ++n)
        biasr[n] = bias[colBase + wn * 32 + n * 16 + l15];

    asm volatile("s_waitcnt vmcnt(0)" ::: "memory");
    __builtin_amdgcn_s_barrier();

    int buf = 0;
    for (int rt = ib; rt < NT_; rt += 256) {
        int rtn = rt + 256;
        if (rtn < NT_) stageA(rtn, buf ^ 1);

        f32x4 acc[4][2] = {};
        #pragma unroll
        for (int ks = 0; ks < 8; ++ks) {
            short8 af[4];
            #pragma unroll
            for (int m = 0; m < 4; ++m) {
                int row = m * 16 + l15;
                af[m] = *(const short8*)&As[buf][row * 256 + (((ks * 4 + lq) ^ (row & 7)) * 8)];
            }
            #pragma unroll
            for (int m = 0; m < 4; ++m)
                #pragma unroll
                for (int n = 0; n < 2; ++n)
                    acc[m][n] = __builtin_amdgcn_mfma_f32_16x16x32_bf16(af[m], bf[n][ks], acc[m][n], 0, 0, 0);
        }
        asm volatile("s_waitcnt lgkmcnt(0)" ::: "memory");
        __builtin_amdgcn_s_barrier();

        if constexpr (OUT_BF16) {
            __hip_bfloat16* Cs = &As[buf][0];  // [64][136]
            #pragma unroll
            for (int m = 0; m < 4; ++m)
                #pragma unroll
                for (int n = 0; n < 2; ++n) {
                    int col = wn * 32 + n * 16 + l15;
                    #pragma unroll
                    for (int j = 0; j < 4; ++j)
                        Cs[(m * 16 + lq * 4 + j) * 136 + col] =
                            __float2bfloat16(acc[m][n][j] + biasr[n]);
                }
            asm volatile("s_waitcnt lgkmcnt(0)" ::: "memory");
            __builtin_amdgcn_s_barrier();
            int row = tid >> 2, cq = tid & 3;
            __hip_bfloat16* og = (__hip_bfloat16*)outp + ((size_t)rt * 64 + row) * NCOLS + colBase;
            #pragma unroll
            for (int i = 0; i < 4; ++i) {
                int col = cq * 8 + i * 32;
                *(short8*)&og[col] = *(const short8*)&Cs[row * 136 + col];
            }
            asm volatile("s_waitcnt vmcnt(2) lgkmcnt(0)" ::: "memory");
            __builtin_amdgcn_s_barrier();
        } else {
            float* Cs = (float*)&As[buf][0];   // [32][132] per pass
            #pragma unroll
            for (int pp = 0; pp < 2; ++pp) {
                #pragma unroll
                for (int mm = 0; mm < 2; ++mm) {
                    int m = 2 * pp + mm;
                    #pragma unroll
                    for (int n = 0; n < 2; ++n) {
                        int col = wn * 32 + n * 16 + l15;
                        #pragma unroll
                        for (int j = 0; j < 4; ++j)
                            Cs[(mm * 16 + lq * 4 + j) * 132 + col] = acc[m][n][j] + biasr[n];
                    }
                }
                asm volatile("s_waitcnt lgkmcnt(0)" ::: "memory");
                __builtin_amdgcn_s_barrier();
                int row = tid >> 3, k = tid & 7;
                float* og = (float*)outp + ((size_t)rt * 64 + pp * 32 + row) * NCOLS + colBase;
                #pragma unroll
                for (int i = 0; i < 4; ++i) {
                    int col = k * 4 + i * 32;
                    *(float4*)&og[col] = *(const float4*)&Cs[row * 132 + col];
                }
                asm volatile("s_waitcnt lgkmcnt(0)" ::: "memory");
                __builtin_amdgcn_s_barrier();
            }
            asm volatile("s_waitcnt vmcnt(4) lgkmcnt(0)" ::: "memory");
            __builtin_amdgcn_s_barrier();
        }
        buf ^= 1;
    }
}

// ---------------------------------------------------------------------------
// MFMA reduce_kv (R8): one block per bt, 8 waves = 8 heads.
// ---------------------------------------------------------------------------
__global__ __launch_bounds__(512, 2)
void reduce_kv(const __hip_bfloat16* __restrict__ qkv, __hip_bfloat16* __restrict__ kv2t,
               float* __restrict__ vmeanb) {
    __shared__ __align__(16) __hip_bfloat16 T[512 * 64];   // 64 KB
    const int bt = blockIdx.x;
    const int tid = threadIdx.x;
    const int lane = tid & 63;
    const int h = tid >> 6;
    const int l15 = lane & 15, lq = lane >> 4;
    const int co = tid >> 3;
    const int np3 = tid & 7;
    const size_t rowbase = (size_t)bt * N_;

    union S8 { short8 v; unsigned short u[8]; };
    const short8 zero8 = {0, 0, 0, 0, 0, 0, 0, 0};

    auto issue_loads = [&](int n0, S8* Aq, S8* Bq) {
        #pragma unroll
        for (int s = 0; s < 4; ++s) {
            int n = n0 + 2 * (np3 + 8 * s);
            Aq[s].v = (n < N_)     ? *(const short8*)&qkv[(rowbase + n) * 768 + 256 + co * 8] : zero8;
            Bq[s].v = (n + 1 < N_) ? *(const short8*)&qkv[(rowbase + n + 1) * 768 + 256 + co * 8] : zero8;
        }
    };
    auto write_lds = [&](S8* Aq, S8* Bq) {
        #pragma unroll
        for (int s = 0; s < 4; ++s) {
            int r = 2 * (np3 + 8 * s);
            int slotbase = ((r >> 3));
            #pragma unroll
            for (int j = 0; j < 8; ++j) {
                int c = co * 8 + j;
                u32 wv = (u32)Aq[s].u[j] | ((u32)Bq[s].u[j] << 16);
                int off = c * 64 + ((slotbase ^ (c & 7)) << 3) + (r & 7);
                *(u32*)&T[off] = wv;
            }
        }
    };

    S8 bufA[4], bufB[4], nxtA[4], nxtB[4];
    issue_loads(0, bufA, bufB);

    f32x4 acc[2][2] = {};
    f32x4 acck[2] = {};
    f32x4 accv[2] = {};
    S8 ones;
    #pragma unroll
    for (int j = 0; j < 8; ++j) ones.u[j] = 0x3F80;   // bf16 1.0

    for (int chunk = 0; chunk < 12; ++chunk) {
        if (chunk < 11) issue_loads((chunk + 1) * 64, nxtA, nxtB);
        write_lds(bufA, bufB);
        __syncthreads();
        #pragma unroll
        for (int nc = 0; nc < 2; ++nc) {
            short8 af[2], bfr[2];
            int slot = nc * 4 + lq;
            #pragma unroll
            for (int dh = 0; dh < 2; ++dh) {
                int c = h * 32 + dh * 16 + l15;
                af[dh] = *(const short8*)&T[c * 64 + ((slot ^ (c & 7)) << 3)];
            }
            #pragma unroll
            for (int eh = 0; eh < 2; ++eh) {
                int c = 256 + h * 32 + eh * 16 + l15;
                bfr[eh] = *(const short8*)&T[c * 64 + ((slot ^ (c & 7)) << 3)];
            }
            #pragma unroll
            for (int dh = 0; dh < 2; ++dh)
                #pragma unroll
                for (int eh = 0; eh < 2; ++eh)
                    acc[dh][eh] = __builtin_amdgcn_mfma_f32_16x16x32_bf16(af[dh], bfr[eh], acc[dh][eh], 0, 0, 0);
            #pragma unroll
            for (int dh = 0; dh < 2; ++dh)
                acck[dh] = __builtin_amdgcn_mfma_f32_16x16x32_bf16(af[dh], ones.v, acck[dh], 0, 0, 0);
            #pragma unroll
            for (int eh = 0; eh < 2; ++eh)
                accv[eh] = __builtin_amdgcn_mfma_f32_16x16x32_bf16(ones.v, bfr[eh], accv[eh], 0, 0, 0);
        }
        __syncthreads();
        #pragma unroll
        for (int s = 0; s < 4; ++s) { bufA[s] = nxtA[s]; bufB[s] = nxtB[s]; }
    }

    const int bh = bt * 8 + h;
    #pragma unroll
    for (int eh = 0; eh < 2; ++eh) {
        int e = eh * 16 + l15;
        float vme = accv[eh][0] * INVN_;
        #pragma unroll
        for (int dh = 0; dh < 2; ++dh) {
            union { sv4 v; __hip_bfloat16 x[4]; } o;
            #pragma unroll
            for (int j = 0; j < 4; ++j) {
                float km = acck[dh][j] * INVN_;
                float val = acc[dh][eh][j] * (SCALE_ * INVN_) - SCALE_ * km * vme;
                o.x[j] = __float2bfloat16(val);
            }
            *(sv4*)&kv2t[(size_t)bh * 1024 + e * 32 + dh * 16 + lq * 4] = o.v;
        }
        if (lq == 0) vmeanb[bh * 32 + e] = vme;
    }
}

// ---------------------------------------------------------------------------
// fuse_zout v2: attn -> in-place conv -> out projection on one 64x256 LDS
// tile. NEW vs R18: (a) all v rows + rw taps PREFETCHED into registers
// before phase 1 (their HBM latency hides under the attn MFMAs), phase 2 is
// pure VALU + 16B LDS RMW; (b) conv repartitioned to 4 rows x 8 ch/thread;
// (c) Wo fragments loaded AFTER phase 2 (keeps peak VGPR < 128).
// grid (384, 12), block 512 (8 waves). LDS = 32KB AZ + 17KB RB.
// ---------------------------------------------------------------------------
__global__ __launch_bounds__(512, 2)
void fuse_zout(const __hip_bfloat16* __restrict__ qkv, const __hip_bfloat16* __restrict__ kv2t,
               const float* __restrict__ vmeanb, const float* __restrict__ rw,
               const __hip_bfloat16* __restrict__ wo, const float* __restrict__ bo,
               float* __restrict__ outp) {
    __shared__ __align__(16) __hip_bfloat16 AZ[64 * 256];   // 32 KB, swizzled tile
    __shared__ __align__(16) char RB[17408];                // kvl 16KB -> Cs f32[16][264]
    __hip_bfloat16* kvl = (__hip_bfloat16*)RB;

    const int bt = blockIdx.x;
    const int n0 = blockIdx.y * 64;
    const int rows = (N_ - n0 < 64) ? (N_ - n0) : 64;
    const int t = threadIdx.x;
    const int lane = t & 63;
    const int w = t >> 6;                 // wave 0..7
    const int l15 = lane & 15, lq = lane >> 4;
    const size_t rowbase = (size_t)bt * N_;

    // ---- conv-thread geometry: 16 row-groups x 32 channel-octs ----
    const int tr = t >> 5;                // 0..15, rows tr*4 .. tr*4+4
    const int c8 = (t & 31) * 8;          // channel oct
    const int rbeg = tr * 4;

    // ---- PREFETCH (issued before phase 1; lands under the MFMAs) ----
    union S8 { short8 v; __hip_bfloat16 h[8]; };
    const short8 zero8 = {0, 0, 0, 0, 0, 0, 0, 0};
    S8 vreg[6];                           // v rows n0+rbeg-1 .. n0+rbeg+4
    #pragma unroll
    for (int i = 0; i < 6; ++i) {
        int gn = n0 + rbeg - 1 + i;
        vreg[i].v = (gn >= 0 && gn < N_)
            ? *(const short8*)&qkv[(rowbase + gn) * 768 + 512 + c8] : zero8;
    }
    float w0[8], w1_[8], w2_[8];
    #pragma unroll
    for (int u = 0; u < 8; ++u) {
        w0[u]  = rw[bt * 768 + (c8 + u) * 3 + 0];
        w1_[u] = rw[bt * 768 + (c8 + u) * 3 + 1];
        w2_[u] = rw[bt * 768 + (c8 + u) * 3 + 2];
    }

    // stage kv2t[bt] slice (16 KB)
    {
        const __hip_bfloat16* src = kv2t + (size_t)bt * 8192;
        #pragma unroll
        for (int i = 0; i < 2; ++i) {
            int off = (t + i * 512) * 8;
            *(short8*)&kvl[off] = *(const short8*)&src[off];
        }
    }
    __syncthreads();

    // ---- phase 1: attn = q @ kv2t + vmean -> AZ (swizzled) ----
    {
        int r0 = (w & 3) * 16;            // wave's 16-row slice
        int hb = (w >> 2) * 4;            // wave's 4 heads
        int gn = n0 + r0 + l15; if (gn > N_ - 1) gn = N_ - 1;
        const __hip_bfloat16* qrow = qkv + (rowbase + gn) * 768;
        #pragma unroll
        for (int hh = 0; hh < 4; ++hh) {
            int h = hb + hh;
            short8 af = *(const short8*)&qrow[h * 32 + lq * 8];
            #pragma unroll
            for (int half = 0; half < 2; ++half) {
                short8 kb = *(const short8*)&kvl[h * 1024 + (half * 16 + l15) * 32 + lq * 8];
                f32x4 a = {};
                a = __builtin_amdgcn_mfma_f32_16x16x32_bf16(af, kb, a, 0, 0, 0);
                int col = h * 32 + half * 16 + l15;
                float vm = vmeanb[bt * 256 + col];
                #pragma unroll
                for (int j = 0; j < 4; ++j) {
                    int r = r0 + lq * 4 + j;
                    AZ[r * 256 + ((((col >> 3) ^ (r & 7)) << 3) | (col & 7))] =
                        __float2bfloat16(a[j] + vm);
                }
            }
        }
    }
    __syncthreads();

    // ---- phase 2: in-place conv from prefetched registers (pure VALU+LDS) ----
    if (rbeg < rows) {
        float vp[8], vc[8], vn[8];
        #pragma unroll
        for (int u = 0; u < 8; ++u) {
            vp[u] = __bfloat162float(vreg[0].h[u]);
            vc[u] = __bfloat162float(vreg[1].h[u]);
        }
        #pragma unroll
        for (int ri = 0; ri < 4; ++ri) {
            int r = rbeg + ri;
            if (r < rows) {
                #pragma unroll
                for (int u = 0; u < 8; ++u) vn[u] = __bfloat162float(vreg[ri + 2].h[u]);
                int base = r * 256 + (((c8 >> 3) ^ (r & 7)) << 3);
                S8 az; az.v = *(const short8*)&AZ[base];
                S8 zv;
                #pragma unroll
                for (int u = 0; u < 8; ++u) {
                    float s = __bfloat162float(az.h[u]) + w0[u] * vp[u]
                              + w1_[u] * vc[u] + w2_[u] * vn[u];
                    zv.h[u] = __float2bfloat16(s);
                }
                *(short8*)&AZ[base] = zv.v;
                #pragma unroll
                for (int u = 0; u < 8; ++u) { vp[u] = vc[u]; vc[u] = vn[u]; }
            }
        }
    }
    __syncthreads();

    // ---- Wo fragments + bias (loaded late; L2-hot) ----
    short8 bf[2][8];
    #pragma unroll
    for (int n = 0; n < 2; ++n)
        #pragma unroll
        for (int ks = 0; ks < 8; ++ks)
            bf[n][ks] = *(const short8*)&wo[(size_t)(w * 32 + n * 16 + l15) * 256 + ks * 32 + lq * 8];
    float biasr[2];
    #pragma unroll
    for (int n = 0; n < 2; ++n) biasr[n] = bo[w * 32 + n * 16 + l15];

    // ---- phase 3: out = Z @ Wo^T + bo; A from AZ (LDS), B in regs ----
    f32x4 acc[4][2] = {};
    #pragma unroll
    for (int ks = 0; ks < 8; ++ks) {
        short8 af[4];
        #pragma unroll
        for (int m = 0; m < 4; ++m) {
            int row = m * 16 + l15;
            af[m] = *(const short8*)&AZ[row * 256 + (((ks * 4 + lq) ^ (row & 7)) << 3)];
        }
        #pragma unroll
        for (int m = 0; m < 4; ++m)
            #pragma unroll
            for (int n = 0; n < 2; ++n)
                acc[m][n] = __builtin_amdgcn_mfma_f32_16x16x32_bf16(af[m], bf[n][ks], acc[m][n], 0, 0, 0);
    }

    // ---- epilogue: 4 passes of 16 rows through Cs[16][264] (kvl dead) ----
    float* Cs = (float*)RB;   // 16 * 264 * 4 = 16896 B <= 17408 B
    #pragma unroll
    for (int pp = 0; pp < 4; ++pp) {
        asm volatile("s_waitcnt lgkmcnt(0)" ::: "memory");
        __builtin_amdgcn_s_barrier();     // region free / prev-pass reads done
        #pragma unroll
        for (int n = 0; n < 2; ++n) {
            int col = w * 32 + n * 16 + l15;
            #pragma unroll
            for (int j = 0; j < 4; ++j)
                Cs[(lq * 4 + j) * 264 + col] = acc[pp][n][j] + biasr[n];
        }
        asm volatile("s_waitcnt lgkmcnt(0)" ::: "memory");
        __builtin_amdgcn_s_barrier();
        int row = t >> 5, kk = t & 31;    // 16 rows x 32 col-quads
        int grow = pp * 16 + row;
        if (grow < rows) {
            float* og = outp + (rowbase + n0 + grow) * 256;
            #pragma unroll
            for (int i = 0; i < 2; ++i) {
                int col = kk * 4 + i * 128;
                *(float4*)&og[col] = *(const float4*)&Cs[row * 264 + col];
            }
        }
    }
}

// ---------------------------------------------------------------------------
extern "C" void kernel_launch(void* const* d_in, const int* in_sizes, int n_in,
                              void* d_out, int out_size, void* d_ws, size_t ws_size,
                              hipStream_t stream) {
    (void)in_sizes; (void)n_in; (void)out_size; (void)ws_size;
    const float* x  = (const float*)d_in[0];
    const float* Wq = (const float*)d_in[1];  const float* bq = (const float*)d_in[2];
    const float* Wk = (const float*)d_in[3];  const float* bk = (const float*)d_in[4];
    const float* Wv = (const float*)d_in[5];  const float* bv = (const float*)d_in[6];
    const float* Wo = (const float*)d_in[7];  const float* bo = (const float*)d_in[8];
    const float* w1 = (const float*)d_in[9];  const float* b1 = (const float*)d_in[10];
    const float* w2 = (const float*)d_in[11]; const float* b2 = (const float*)d_in[12];
    float* out = (float*)d_out;

    char* ws = (char*)d_ws;
    size_t off = 0;
    auto take = [&](size_t bytes) -> char* {
        char* p = ws + off;
        off = (off + bytes + 255) & ~(size_t)255;
        return p;
    };

    __hip_bfloat16* qkv   = (__hip_bfloat16*)take((size_t)MROWS * 768 * 2);
    __hip_bfloat16* xb    = (__hip_bfloat16*)take((size_t)MROWS * 256 * 2);
    __hip_bfloat16* wqkv  = (__hip_bfloat16*)take(768 * 256 * 2);
    __hip_bfloat16* wo    = (__hip_bfloat16*)take(256 * 256 * 2);
    float* bqkv   = (float*)take(768 * 4);
    float* msum   = (float*)take(384 * 256 * 4);
    float* rw     = (float*)take(384 * 768 * 4);
    __hip_bfloat16* kv2t = (__hip_bfloat16*)take((size_t)384 * 8192 * 2);
    float* vmeanb = (float*)take(384 * 256 * 4);

    hipMemsetAsync(msum, 0, 384 * 256 * 4, stream);

    prep_weights<<<768, 256, 0, stream>>>(Wq, bq, Wk, bk, Wv, bv, Wo, wqkv, bqkv, wo);
    convert_x<<<dim3(384, 4), 256, 0, stream>>>(x, xb, msum);
    mlp_rw<<<384, 256, 0, stream>>>(msum, w1, b1, w2, b2, rw);
    // QKV projection: [274944,256] x [768,256]^T -> bf16 qkv, bias fused
    gemm_persist<768, 6, true><<<1536, 256, 0, stream>>>(xb, wqkv, bqkv, qkv);
    reduce_kv<<<384, 512, 0, stream>>>(qkv, kv2t, vmeanb);
    // Fused: attn + conv + output projection -> out (f32), Z never materialized
    fuse_zout<<<dim3(384, 12), 512, 0, stream>>>(qkv, kv2t, vmeanb, rw, wo, bo, out);
}

// Round 20
// 525.724 us; speedup vs baseline: 1.0545x; 1.0017x over previous
//
#include <hip/hip_runtime.h>
#include <hip/hip_bf16.h>
#include <math.h>

typedef __attribute__((ext_vector_type(8))) short short8;
typedef __attribute__((ext_vector_type(4))) short sv4;
typedef __attribute__((ext_vector_type(4))) float f32x4;
typedef unsigned int u32;

#define BT_ 384
#define N_ 716
#define C_ 256
#define H_ 8
#define D_ 32
#define MROWS (BT_ * N_)   /* 274944 */
#define NT_ (MROWS / 64)   /* 4296 row-tiles of 64 */
#define SCALE_ 0.17677669529663687f  /* 32^-0.5 */
#define INVN_ (1.0f / 716.0f)

__device__ __forceinline__ void gload_lds16(const void* g, void* l) {
    __builtin_amdgcn_global_load_lds(
        (const __attribute__((address_space(1))) u32*)g,
        (__attribute__((address_space(3))) u32*)l, 16, 0, 0);
}

// ---------------------------------------------------------------------------
// Assemble bf16 weight matrices + fused qkv bias. Wqkv_b[768][256], Wo_b[256][256]
// ---------------------------------------------------------------------------
__global__ void prep_weights(const float* __restrict__ Wq, const float* __restrict__ bq,
                             const float* __restrict__ Wk, const float* __restrict__ bk,
                             const float* __restrict__ Wv, const float* __restrict__ bv,
                             const float* __restrict__ Wo,
                             __hip_bfloat16* __restrict__ wqkv, float* __restrict__ bqkv,
                             __hip_bfloat16* __restrict__ wo) {
    int idx = blockIdx.x * 256 + threadIdx.x;
    if (idx < 768 * 256) {
        int o = idx >> 8, c = idx & 255;
        const float* W = (o < 256) ? Wq : ((o < 512) ? Wk : Wv);
        int oo = o & 255;
        wqkv[idx] = __float2bfloat16(W[oo * 256 + c]);
    }
    if (idx < 256 * 256) wo[idx] = __float2bfloat16(Wo[idx]);
    if (idx < 768) bqkv[idx] = (idx < 256) ? bq[idx] : ((idx < 512) ? bk[idx - 256] : bv[idx - 512]);
}

// ---------------------------------------------------------------------------
// x fp32 -> bf16 (vectorized float4/short4), plus per-(bt,channel) col sums
// grid (384, 4), block 256.
// ---------------------------------------------------------------------------
__global__ __launch_bounds__(256)
void convert_x(const float* __restrict__ x, __hip_bfloat16* __restrict__ xb,
               float* __restrict__ msum) {
    int bt = blockIdx.x, chunk = blockIdx.y;
    int t = threadIdx.x;
    int c4 = (t & 63) * 4;
    int r0 = t >> 6;
    size_t base = ((size_t)bt * N_ + (size_t)chunk * 179) * C_;
    float s0 = 0.f, s1 = 0.f, s2 = 0.f, s3 = 0.f;
    for (int r = r0; r < 179; r += 4) {
        float4 f = *(const float4*)&x[base + (size_t)r * C_ + c4];
        union { sv4 v; __hip_bfloat16 h[4]; } u;
        u.h[0] = __float2bfloat16(f.x);
        u.h[1] = __float2bfloat16(f.y);
        u.h[2] = __float2bfloat16(f.z);
        u.h[3] = __float2bfloat16(f.w);
        *(sv4*)&xb[base + (size_t)r * C_ + c4] = u.v;
        s0 += f.x; s1 += f.y; s2 += f.z; s3 += f.w;
    }
    atomicAdd(&msum[bt * C_ + c4 + 0], s0);
    atomicAdd(&msum[bt * C_ + c4 + 1], s1);
    atomicAdd(&msum[bt * C_ + c4 + 2], s2);
    atomicAdd(&msum[bt * C_ + c4 + 3], s3);
}

// ---------------------------------------------------------------------------
// Grouped 2-layer MLP -> per-channel 3-tap conv weights rw[bt][768]
// ---------------------------------------------------------------------------
__global__ __launch_bounds__(256)
void mlp_rw(const float* __restrict__ msum, const float* __restrict__ w1,
            const float* __restrict__ b1, const float* __restrict__ w2,
            const float* __restrict__ b2, float* __restrict__ rw) {
    int bt = blockIdx.x;
    int t = threadIdx.x;
    __shared__ float m_l[256];
    __shared__ float h1_l[256];
    m_l[t] = msum[bt * 256 + t] * INVN_;
    __syncthreads();
    int g = t >> 5;
    float a = b1[t];
    #pragma unroll
    for (int i = 0; i < 32; ++i) a += m_l[g * 32 + i] * w1[t * 32 + i];
    h1_l[t] = 0.5f * a * (1.0f + erff(a * 0.70710678118654752f));
    __syncthreads();
    for (int o = t; o < 768; o += 256) {
        int gg = o / 96;
        float s = b2[o];
        #pragma unroll
        for (int i = 0; i < 32; ++i) s += h1_l[gg * 32 + i] * w2[o * 32 + i];
        rw[bt * 768 + o] = s;
    }
}

// ---------------------------------------------------------------------------
// Persistent B-resident GEMM v2 (R9/R15, best measured). bf16 output path
// used for the QKV projection. grid GRIDX*256, block 256.
// ---------------------------------------------------------------------------
template<int NCOLS, int GRIDX, bool OUT_BF16>
__global__ __launch_bounds__(256, 2)
void gemm_persist(const __hip_bfloat16* __restrict__ A, const __hip_bfloat16* __restrict__ Bm,
                  const float* __restrict__ bias, void* __restrict__ outp) {
    __shared__ __align__(16) __hip_bfloat16 As[2][64 * 256];   // 2 x 32KB
    const int L = blockIdx.x;
    const int xcd = L & 7, w = L >> 3;
    const int cb = w % GRIDX;
    const int ib = xcd * 32 + w / GRIDX;
    const int tid = threadIdx.x;
    const int lane = tid & 63;
    const int wave = tid >> 6;
    const int wn = wave;
    const int colBase = cb * 128;
    const int l15 = lane & 15, lq = lane >> 4;
    const int lrow2 = lane >> 5;
    const int p = lane & 31;

    auto stageA = [&](int rt, int buf) {
        #pragma unroll
        for (int i = 0; i < 8; ++i) {
            int r = wave * 16 + 2 * i + lrow2;
            const __hip_bfloat16* g = A + ((size_t)rt * 64 + r) * 256 + ((p ^ (r & 7)) * 8);
            gload_lds16(g, &As[buf][(wave * 16 + 2 * i) * 256]);
        }
    };

    stageA(ib, 0);

    short8 bf[2][8];
    #pragma unroll
    for (int n = 0; n < 2; ++n)
        #pragma unroll
        for (int ks = 0; ks < 8; ++ks)
            bf[n][ks] = *(const short8*)&Bm[(size_t)(colBase + wn * 32 + n * 16 + l15) * 256 + ks * 32 + lq * 8];
    float biasr[2];
    #pragma unroll
    for (int n = 0; n < 2; ++n)
        biasr[n] = bias[colBase + wn * 32 + n * 16 + l15];

    asm volatile("s_waitcnt vmcnt(0)" ::: "memory");
    __builtin_amdgcn_s_barrier();

    int buf = 0;
    for (int rt = ib; rt < NT_; rt += 256) {
        int rtn = rt + 256;
        if (rtn < NT_) stageA(rtn, buf ^ 1);

        f32x4 acc[4][2] = {};
        #pragma unroll
        for (int ks = 0; ks < 8; ++ks) {
            short8 af[4];
            #pragma unroll
            for (int m = 0; m < 4; ++m) {
                int row = m * 16 + l15;
                af[m] = *(const short8*)&As[buf][row * 256 + (((ks * 4 + lq) ^ (row & 7)) * 8)];
            }
            #pragma unroll
            for (int m = 0; m < 4; ++m)
                #pragma unroll
                for (int n = 0; n < 2; ++n)
                    acc[m][n] = __builtin_amdgcn_mfma_f32_16x16x32_bf16(af[m], bf[n][ks], acc[m][n], 0, 0, 0);
        }
        asm volatile("s_waitcnt lgkmcnt(0)" ::: "memory");
        __builtin_amdgcn_s_barrier();

        if constexpr (OUT_BF16) {
            __hip_bfloat16* Cs = &As[buf][0];  // [64][136]
            #pragma unroll
            for (int m = 0; m < 4; ++m)
                #pragma unroll
                for (int n = 0; n < 2; ++n) {
                    int col = wn * 32 + n * 16 + l15;
                    #pragma unroll
                    for (int j = 0; j < 4; ++j)
                        Cs[(m * 16 + lq * 4 + j) * 136 + col] =
                            __float2bfloat16(acc[m][n][j] + biasr[n]);
                }
            asm volatile("s_waitcnt lgkmcnt(0)" ::: "memory");
            __builtin_amdgcn_s_barrier();
            int row = tid >> 2, cq = tid & 3;
            __hip_bfloat16* og = (__hip_bfloat16*)outp + ((size_t)rt * 64 + row) * NCOLS + colBase;
            #pragma unroll
            for (int i = 0; i < 4; ++i) {
                int col = cq * 8 + i * 32;
                *(short8*)&og[col] = *(const short8*)&Cs[row * 136 + col];
            }
            asm volatile("s_waitcnt vmcnt(2) lgkmcnt(0)" ::: "memory");
            __builtin_amdgcn_s_barrier();
        } else {
            float* Cs = (float*)&As[buf][0];   // [32][132] per pass
            #pragma unroll
            for (int pp = 0; pp < 2; ++pp) {
                #pragma unroll
                for (int mm = 0; mm < 2; ++mm) {
                    int m = 2 * pp + mm;
                    #pragma unroll
                    for (int n = 0; n < 2; ++n) {
                        int col = wn * 32 + n * 16 + l15;
                        #pragma unroll
                        for (int j = 0; j < 4; ++j)
                            Cs[(mm * 16 + lq * 4 + j) * 132 + col] = acc[m][n][j] + biasr[n];
                    }
                }
                asm volatile("s_waitcnt lgkmcnt(0)" ::: "memory");
                __builtin_amdgcn_s_barrier();
                int row = tid >> 3, k = tid & 7;
                float* og = (float*)outp + ((size_t)rt * 64 + pp * 32 + row) * NCOLS + colBase;
                #pragma unroll
                for (int i = 0; i < 4; ++i) {
                    int col = k * 4 + i * 32;
                    *(float4*)&og[col] = *(const float4*)&Cs[row * 132 + col];
                }
                asm volatile("s_waitcnt lgkmcnt(0)" ::: "memory");
                __builtin_amdgcn_s_barrier();
            }
            asm volatile("s_waitcnt vmcnt(4) lgkmcnt(0)" ::: "memory");
            __builtin_amdgcn_s_barrier();
        }
        buf ^= 1;
    }
}

// ---------------------------------------------------------------------------
// MFMA reduce_kv (R8): one block per bt, 8 waves = 8 heads.
// ---------------------------------------------------------------------------
__global__ __launch_bounds__(512, 2)
void reduce_kv(const __hip_bfloat16* __restrict__ qkv, __hip_bfloat16* __restrict__ kv2t,
               float* __restrict__ vmeanb) {
    __shared__ __align__(16) __hip_bfloat16 T[512 * 64];   // 64 KB
    const int bt = blockIdx.x;
    const int tid = threadIdx.x;
    const int lane = tid & 63;
    const int h = tid >> 6;
    const int l15 = lane & 15, lq = lane >> 4;
    const int co = tid >> 3;
    const int np3 = tid & 7;
    const size_t rowbase = (size_t)bt * N_;

    union S8 { short8 v; unsigned short u[8]; };
    const short8 zero8 = {0, 0, 0, 0, 0, 0, 0, 0};

    auto issue_loads = [&](int n0, S8* Aq, S8* Bq) {
        #pragma unroll
        for (int s = 0; s < 4; ++s) {
            int n = n0 + 2 * (np3 + 8 * s);
            Aq[s].v = (n < N_)     ? *(const short8*)&qkv[(rowbase + n) * 768 + 256 + co * 8] : zero8;
            Bq[s].v = (n + 1 < N_) ? *(const short8*)&qkv[(rowbase + n + 1) * 768 + 256 + co * 8] : zero8;
        }
    };
    auto write_lds = [&](S8* Aq, S8* Bq) {
        #pragma unroll
        for (int s = 0; s < 4; ++s) {
            int r = 2 * (np3 + 8 * s);
            int slotbase = ((r >> 3));
            #pragma unroll
            for (int j = 0; j < 8; ++j) {
                int c = co * 8 + j;
                u32 wv = (u32)Aq[s].u[j] | ((u32)Bq[s].u[j] << 16);
                int off = c * 64 + ((slotbase ^ (c & 7)) << 3) + (r & 7);
                *(u32*)&T[off] = wv;
            }
        }
    };

    S8 bufA[4], bufB[4], nxtA[4], nxtB[4];
    issue_loads(0, bufA, bufB);

    f32x4 acc[2][2] = {};
    f32x4 acck[2] = {};
    f32x4 accv[2] = {};
    S8 ones;
    #pragma unroll
    for (int j = 0; j < 8; ++j) ones.u[j] = 0x3F80;   // bf16 1.0

    for (int chunk = 0; chunk < 12; ++chunk) {
        if (chunk < 11) issue_loads((chunk + 1) * 64, nxtA, nxtB);
        write_lds(bufA, bufB);
        __syncthreads();
        #pragma unroll
        for (int nc = 0; nc < 2; ++nc) {
            short8 af[2], bfr[2];
            int slot = nc * 4 + lq;
            #pragma unroll
            for (int dh = 0; dh < 2; ++dh) {
                int c = h * 32 + dh * 16 + l15;
                af[dh] = *(const short8*)&T[c * 64 + ((slot ^ (c & 7)) << 3)];
            }
            #pragma unroll
            for (int eh = 0; eh < 2; ++eh) {
                int c = 256 + h * 32 + eh * 16 + l15;
                bfr[eh] = *(const short8*)&T[c * 64 + ((slot ^ (c & 7)) << 3)];
            }
            #pragma unroll
            for (int dh = 0; dh < 2; ++dh)
                #pragma unroll
                for (int eh = 0; eh < 2; ++eh)
                    acc[dh][eh] = __builtin_amdgcn_mfma_f32_16x16x32_bf16(af[dh], bfr[eh], acc[dh][eh], 0, 0, 0);
            #pragma unroll
            for (int dh = 0; dh < 2; ++dh)
                acck[dh] = __builtin_amdgcn_mfma_f32_16x16x32_bf16(af[dh], ones.v, acck[dh], 0, 0, 0);
            #pragma unroll
            for (int eh = 0; eh < 2; ++eh)
                accv[eh] = __builtin_amdgcn_mfma_f32_16x16x32_bf16(ones.v, bfr[eh], accv[eh], 0, 0, 0);
        }
        __syncthreads();
        #pragma unroll
        for (int s = 0; s < 4; ++s) { bufA[s] = nxtA[s]; bufB[s] = nxtB[s]; }
    }

    const int bh = bt * 8 + h;
    #pragma unroll
    for (int eh = 0; eh < 2; ++eh) {
        int e = eh * 16 + l15;
        float vme = accv[eh][0] * INVN_;
        #pragma unroll
        for (int dh = 0; dh < 2; ++dh) {
            union { sv4 v; __hip_bfloat16 x[4]; } o;
            #pragma unroll
            for (int j = 0; j < 4; ++j) {
                float km = acck[dh][j] * INVN_;
                float val = acc[dh][eh][j] * (SCALE_ * INVN_) - SCALE_ * km * vme;
                o.x[j] = __float2bfloat16(val);
            }
            *(sv4*)&kv2t[(size_t)bh * 1024 + e * 32 + dh * 16 + lq * 4] = o.v;
        }
        if (lq == 0) vmeanb[bh * 32 + e] = vme;
    }
}

// ---------------------------------------------------------------------------
// fuse_zout v3: attn -> in-place conv -> out projection on one 64x256 LDS
// tile. NEW vs R19: LDS cut to 48KB (3 blocks/CU) — the f32 epilogue Cs now
// reuses the DEAD AZ tile (fenced by the pass-0 lgkmcnt(0)+barrier); RB holds
// only the 16KB kvl slice.
// grid (384, 12), block 512 (8 waves). LDS = 32KB AZ + 16KB RB = 48KB.
// ---------------------------------------------------------------------------
__global__ __launch_bounds__(512, 2)
void fuse_zout(const __hip_bfloat16* __restrict__ qkv, const __hip_bfloat16* __restrict__ kv2t,
               const float* __restrict__ vmeanb, const float* __restrict__ rw,
               const __hip_bfloat16* __restrict__ wo, const float* __restrict__ bo,
               float* __restrict__ outp) {
    __shared__ __align__(16) __hip_bfloat16 AZ[64 * 256];   // 32 KB, swizzled tile
    __shared__ __align__(16) __hip_bfloat16 kvl[8192];      // 16 KB
    const int bt = blockIdx.x;
    const int n0 = blockIdx.y * 64;
    const int rows = (N_ - n0 < 64) ? (N_ - n0) : 64;
    const int t = threadIdx.x;
    const int lane = t & 63;
    const int w = t >> 6;                 // wave 0..7
    const int l15 = lane & 15, lq = lane >> 4;
    const size_t rowbase = (size_t)bt * N_;

    // ---- conv-thread geometry: 16 row-groups x 32 channel-octs ----
    const int tr = t >> 5;                // 0..15, rows tr*4 .. tr*4+4
    const int c8 = (t & 31) * 8;          // channel oct
    const int rbeg = tr * 4;

    // ---- PREFETCH (issued before phase 1; lands under the MFMAs) ----
    union S8 { short8 v; __hip_bfloat16 h[8]; };
    const short8 zero8 = {0, 0, 0, 0, 0, 0, 0, 0};
    S8 vreg[6];                           // v rows n0+rbeg-1 .. n0+rbeg+4
    #pragma unroll
    for (int i = 0; i < 6; ++i) {
        int gn = n0 + rbeg - 1 + i;
        vreg[i].v = (gn >= 0 && gn < N_)
            ? *(const short8*)&qkv[(rowbase + gn) * 768 + 512 + c8] : zero8;
    }
    float w0[8], w1_[8], w2_[8];
    #pragma unroll
    for (int u = 0; u < 8; ++u) {
        w0[u]  = rw[bt * 768 + (c8 + u) * 3 + 0];
        w1_[u] = rw[bt * 768 + (c8 + u) * 3 + 1];
        w2_[u] = rw[bt * 768 + (c8 + u) * 3 + 2];
    }

    // stage kv2t[bt] slice (16 KB)
    {
        const __hip_bfloat16* src = kv2t + (size_t)bt * 8192;
        #pragma unroll
        for (int i = 0; i < 2; ++i) {
            int off = (t + i * 512) * 8;
            *(short8*)&kvl[off] = *(const short8*)&src[off];
        }
    }
    __syncthreads();

    // ---- phase 1: attn = q @ kv2t + vmean -> AZ (swizzled) ----
    {
        int r0 = (w & 3) * 16;            // wave's 16-row slice
        int hb = (w >> 2) * 4;            // wave's 4 heads
        int gn = n0 + r0 + l15; if (gn > N_ - 1) gn = N_ - 1;
        const __hip_bfloat16* qrow = qkv + (rowbase + gn) * 768;
        #pragma unroll
        for (int hh = 0; hh < 4; ++hh) {
            int h = hb + hh;
            short8 af = *(const short8*)&qrow[h * 32 + lq * 8];
            #pragma unroll
            for (int half = 0; half < 2; ++half) {
                short8 kb = *(const short8*)&kvl[h * 1024 + (half * 16 + l15) * 32 + lq * 8];
                f32x4 a = {};
                a = __builtin_amdgcn_mfma_f32_16x16x32_bf16(af, kb, a, 0, 0, 0);
                int col = h * 32 + half * 16 + l15;
                float vm = vmeanb[bt * 256 + col];
                #pragma unroll
                for (int j = 0; j < 4; ++j) {
                    int r = r0 + lq * 4 + j;
                    AZ[r * 256 + ((((col >> 3) ^ (r & 7)) << 3) | (col & 7))] =
                        __float2bfloat16(a[j] + vm);
                }
            }
        }
    }
    __syncthreads();

    // ---- phase 2: in-place conv from prefetched registers (pure VALU+LDS) ----
    if (rbeg < rows) {
        float vp[8], vc[8], vn[8];
        #pragma unroll
        for (int u = 0; u < 8; ++u) {
            vp[u] = __bfloat162float(vreg[0].h[u]);
            vc[u] = __bfloat162float(vreg[1].h[u]);
        }
        #pragma unroll
        for (int ri = 0; ri < 4; ++ri) {
            int r = rbeg + ri;
            if (r < rows) {
                #pragma unroll
                for (int u = 0; u < 8; ++u) vn[u] = __bfloat162float(vreg[ri + 2].h[u]);
                int base = r * 256 + (((c8 >> 3) ^ (r & 7)) << 3);
                S8 az; az.v = *(const short8*)&AZ[base];
                S8 zv;
                #pragma unroll
                for (int u = 0; u < 8; ++u) {
                    float s = __bfloat162float(az.h[u]) + w0[u] * vp[u]
                              + w1_[u] * vc[u] + w2_[u] * vn[u];
                    zv.h[u] = __float2bfloat16(s);
                }
                *(short8*)&AZ[base] = zv.v;
                #pragma unroll
                for (int u = 0; u < 8; ++u) { vp[u] = vc[u]; vc[u] = vn[u]; }
            }
        }
    }
    __syncthreads();

    // ---- Wo fragments + bias (loaded late; L2-hot) ----
    short8 bf[2][8];
    #pragma unroll
    for (int n = 0; n < 2; ++n)
        #pragma unroll
        for (int ks = 0; ks < 8; ++ks)
            bf[n][ks] = *(const short8*)&wo[(size_t)(w * 32 + n * 16 + l15) * 256 + ks * 32 + lq * 8];
    float biasr[2];
    #pragma unroll
    for (int n = 0; n < 2; ++n) biasr[n] = bo[w * 32 + n * 16 + l15];

    // ---- phase 3: out = Z @ Wo^T + bo; A from AZ (LDS), B in regs ----
    f32x4 acc[4][2] = {};
    #pragma unroll
    for (int ks = 0; ks < 8; ++ks) {
        short8 af[4];
        #pragma unroll
        for (int m = 0; m < 4; ++m) {
            int row = m * 16 + l15;
            af[m] = *(const short8*)&AZ[row * 256 + (((ks * 4 + lq) ^ (row & 7)) << 3)];
        }
        #pragma unroll
        for (int m = 0; m < 4; ++m)
            #pragma unroll
            for (int n = 0; n < 2; ++n)
                acc[m][n] = __builtin_amdgcn_mfma_f32_16x16x32_bf16(af[m], bf[n][ks], acc[m][n], 0, 0, 0);
    }

    // ---- epilogue: 4 passes of 16 rows through Cs[16][264] in DEAD AZ ----
    // pass-0's lgkmcnt(0)+barrier fences all phase-3 AZ reads block-wide
    // before the overwrite.
    float* Cs = (float*)AZ;   // 16 * 264 * 4 = 16896 B <= 32768 B
    #pragma unroll
    for (int pp = 0; pp < 4; ++pp) {
        asm volatile("s_waitcnt lgkmcnt(0)" ::: "memory");
        __builtin_amdgcn_s_barrier();     // region free / prev-pass reads done
        #pragma unroll
        for (int n = 0; n < 2; ++n) {
            int col = w * 32 + n * 16 + l15;
            #pragma unroll
            for (int j = 0; j < 4; ++j)
                Cs[(lq * 4 + j) * 264 + col] = acc[pp][n][j] + biasr[n];
        }
        asm volatile("s_waitcnt lgkmcnt(0)" ::: "memory");
        __builtin_amdgcn_s_barrier();
        int row = t >> 5, kk = t & 31;    // 16 rows x 32 col-quads
        int grow = pp * 16 + row;
        if (grow < rows) {
            float* og = outp + (rowbase + n0 + grow) * 256;
            #pragma unroll
            for (int i = 0; i < 2; ++i) {
                int col = kk * 4 + i * 128;
                *(float4*)&og[col] = *(const float4*)&Cs[row * 264 + col];
            }
        }
    }
}

// ---------------------------------------------------------------------------
extern "C" void kernel_launch(void* const* d_in, const int* in_sizes, int n_in,
                              void* d_out, int out_size, void* d_ws, size_t ws_size,
                              hipStream_t stream) {
    (void)in_sizes; (void)n_in; (void)out_size; (void)ws_size;
    const float* x  = (const float*)d_in[0];
    const float* Wq = (const float*)d_in[1];  const float* bq = (const float*)d_in[2];
    const float* Wk = (const float*)d_in[3];  const float* bk = (const float*)d_in[4];
    const float* Wv = (const float*)d_in[5];  const float* bv = (const float*)d_in[6];
    const float* Wo = (const float*)d_in[7];  const float* bo = (const float*)d_in[8];
    const float* w1 = (const float*)d_in[9];  const float* b1 = (const float*)d_in[10];
    const float* w2 = (const float*)d_in[11]; const float* b2 = (const float*)d_in[12];
    float* out = (float*)d_out;

    char* ws = (char*)d_ws;
    size_t off = 0;
    auto take = [&](size_t bytes) -> char* {
        char* p = ws + off;
        off = (off + bytes + 255) & ~(size_t)255;
        return p;
    };

    __hip_bfloat16* qkv   = (__hip_bfloat16*)take((size_t)MROWS * 768 * 2);
    __hip_bfloat16* xb    = (__hip_bfloat16*)take((size_t)MROWS * 256 * 2);
    __hip_bfloat16* wqkv  = (__hip_bfloat16*)take(768 * 256 * 2);
    __hip_bfloat16* wo    = (__hip_bfloat16*)take(256 * 256 * 2);
    float* bqkv   = (float*)take(768 * 4);
    float* msum   = (float*)take(384 * 256 * 4);
    float* rw     = (float*)take(384 * 768 * 4);
    __hip_bfloat16* kv2t = (__hip_bfloat16*)take((size_t)384 * 8192 * 2);
    float* vmeanb = (float*)take(384 * 256 * 4);

    hipMemsetAsync(msum, 0, 384 * 256 * 4, stream);

    prep_weights<<<768, 256, 0, stream>>>(Wq, bq, Wk, bk, Wv, bv, Wo, wqkv, bqkv, wo);
    convert_x<<<dim3(384, 4), 256, 0, stream>>>(x, xb, msum);
    mlp_rw<<<384, 256, 0, stream>>>(msum, w1, b1, w2, b2, rw);
    // QKV projection: [274944,256] x [768,256]^T -> bf16 qkv, bias fused
    gemm_persist<768, 6, true><<<1536, 256, 0, stream>>>(xb, wqkv, bqkv, qkv);
    reduce_kv<<<384, 512, 0, stream>>>(qkv, kv2t, vmeanb);
    // Fused: attn + conv + output projection -> out (f32), Z never materialized
    fuse_zout<<<dim3(384, 12), 512, 0, stream>>>(qkv, kv2t, vmeanb, rw, wo, bo, out);
}